// Round 11
// baseline (31.670 us; speedup 1.0000x reference)
//
#include <hip/hip_runtime.h>
#include <math.h>

// Problem constants (fixed by setup_inputs)
constexpr int B_  = 8;
constexpr int C_  = 64;
constexpr int H_  = 112;
constexpr int W_  = 112;
constexpr int KH  = 5;
constexpr int KW  = 5;
constexpr int PAD = 2;

constexpr int TRR  = 8;             // output rows per tile
constexpr int LR   = TRR + KH - 1;  // 12 staged rows
constexpr int LCP  = 118;           // float2 row stride: even -> every row 16B-aligned
constexpr int TPB  = 128;
constexpr int NTILES = H_ / TRR;    // 14
constexpr int SOUT_LD = 116;        // f32 restage stride (mult of 4)
constexpr int NINT = LR * 28;       // 336 interior float4 staging items

// uniform float -> SGPR: readfirstlane moves BITS (int), so bit-cast both ways.
__device__ __forceinline__ float uniform_f32(float v) {
    return __int_as_float(__builtin_amdgcn_readfirstlane(__float_as_int(v)));
}

// ---------------------------------------------------------------------------
// Fused soft-morphology (func_type==1) via factored softmax:
//   E = e^{a*s*x}, F = (s*x)*E   staged once per input pixel in LDS (float2)
//   u_k = e^{a*w_k}, v_k = w_k*u_k  -> SGPR-resident via bit-cast readfirstlane
//   out = s*( (corr(F,u)+corr(E,v)) * rcp(corr(E,u)) ) + s*bias
// Zero-padded taps => E=1, F=0.
// VGPR target <=64 so 8 waves/SIMD are resident (occupancy steps at 64/128).
// LDS 11328 B -> 14 blocks/CU = 28 waves/CU.
// ---------------------------------------------------------------------------
__global__ __launch_bounds__(TPB, 8)
void morpho_fused(const float* __restrict__ x,
                  const float* __restrict__ weight,
                  const float* __restrict__ bias,
                  const float* __restrict__ sign,
                  const int*   __restrict__ alpha_p,
                  float* __restrict__ out)
{
    // union of EF tile (12*118 float2 = 11328 B) and output restage (8*116 f32)
    __shared__ __align__(16) char smraw[LR * LCP * sizeof(float2)];
    float2 (*sEF)[LCP] = reinterpret_cast<float2 (*)[LCP]>(smraw);

    const int tile  = blockIdx.x;         // 0..13
    const int plane = blockIdx.y;         // 0..511 (b*C + c)
    const int c     = plane & (C_ - 1);
    const int tid   = threadIdx.x;

    const float sg   = sign[0];
    const float seff = (fabsf(sg) >= 1e-7f) ? sg : 1.0f;
    const float a    = (float)alpha_p[0];
    const float aK   = a * seff;          // E = exp(aK * raw_x)

    const float* xp  = x + (size_t)plane * (H_ * W_);
    const int   row0 = tile * TRR - PAD;

    // ---- issue ALL staging global loads first ----
    float4 xv[3];
#pragma unroll
    for (int k = 0; k < 3; ++k) {
        int i  = tid + TPB * k;           // 0..383
        int ic = (i < NINT) ? i : (NINT - 1);
        int r  = ic / 28;
        int q  = ic - r * 28;
        int grc = min(max(row0 + r, 0), H_ - 1);   // clamp -> always in-bounds
        xv[k] = *reinterpret_cast<const float4*>(xp + grc * W_ + 4 * q);
    }

    // ---- block-uniform weight transforms -> SGPRs (overlaps load latency) ----
    const float* wp = weight + c * (KH * KW);
    float su[KH * KW], sv[KH * KW];
#pragma unroll
    for (int k = 0; k < KH * KW; ++k) {
        float wv = wp[k];
        float u  = __expf(a * wv);
        su[k] = uniform_f32(u);           // block-uniform -> SGPR (bit-cast!)
        sv[k] = uniform_f32(wv * u);      // block-uniform -> SGPR (bit-cast!)
    }

    // ---- transform staged pixels and write LDS ----
#pragma unroll
    for (int k = 0; k < 3; ++k) {
        int i = tid + TPB * k;
        if (i < NINT) {
            int r  = i / 28;
            int q  = i - 28 * r;
            int gr = row0 + r;
            bool ok = (gr >= 0) && (gr < H_);
            float4 v = xv[k];
            float e0 = ok ? __expf(aK * v.x) : 1.0f;
            float e1 = ok ? __expf(aK * v.y) : 1.0f;
            float e2 = ok ? __expf(aK * v.z) : 1.0f;
            float e3 = ok ? __expf(aK * v.w) : 1.0f;
            float f0 = ok ? (seff * v.x) * e0 : 0.0f;
            float f1 = ok ? (seff * v.y) * e1 : 0.0f;
            float f2 = ok ? (seff * v.z) * e2 : 0.0f;
            float f3 = ok ? (seff * v.w) * e3 : 0.0f;
            float4* dst = reinterpret_cast<float4*>(&sEF[r][2 + 4 * q]);
            dst[0] = make_float4(e0, f0, e1, f1);
            dst[1] = make_float4(e2, f2, e3, f3);
        }
    }
    // halo columns (image cols -2,-1,112,113 => E=1, F=0): 12 rows x 2 sides
    if (tid >= 104) {                     // 24 threads
        int t = tid - 104;
        int r = t >> 1;
        int fi = (t & 1) ? 114 : 0;       // float2 col; 16B-aligned (LCP even)
        *reinterpret_cast<float4*>(&sEF[r][fi]) = make_float4(1.0f, 0.0f, 1.0f, 0.0f);
    }
    __syncthreads();

    // ---- compute: 1x7 outputs per thread; pure FMA (SGPR weights) + ds_read ----
    const int ty = tid >> 4;      // 0..7 : output row within tile
    const int tx = tid & 15;      // 0..15: col group
    const int c0 = tx * 7;

    float Z[7], Nm[7];
#pragma unroll
    for (int o = 0; o < 7; ++o) { Z[o] = 0.0f; Nm[o] = 0.0f; }

#pragma unroll
    for (int rr = 0; rr < KH; ++rr) {
        float2 ew[11];
#pragma unroll
        for (int jj = 0; jj < 11; ++jj) ew[jj] = sEF[ty + rr][c0 + jj];
#pragma unroll
        for (int j = 0; j < KW; ++j) {
            const float u = su[rr * 5 + j];
            const float v = sv[rr * 5 + j];
#pragma unroll
            for (int o = 0; o < 7; ++o) {
                const float E = ew[o + j].x;
                const float F = ew[o + j].y;
                Z[o]  = fmaf(u, E, Z[o]);
                Nm[o] = fmaf(u, F, fmaf(v, E, Nm[o]));
            }
        }
    }

    // ---- epilogue: rcp + restage to LDS for coalesced float4 stores ----
    __syncthreads();   // all sEF reads done before aliasing as sOut
    float* sOut = reinterpret_cast<float*>(smraw);
    const float sb = seff * bias[c];
#pragma unroll
    for (int o = 0; o < 7; ++o) {
        float val = fmaf(seff * Nm[o], __builtin_amdgcn_rcpf(Z[o]), sb);
        sOut[ty * SOUT_LD + c0 + o] = val;
    }
    __syncthreads();

    float* op = out + (size_t)plane * (H_ * W_) + (size_t)(tile * TRR) * W_;
#pragma unroll
    for (int k = 0; k < 2; ++k) {
        int i = tid + TPB * k;
        if (i < TRR * 28) {               // 224 float4 stores
            int r = i / 28;
            int q = i - 28 * r;
            *reinterpret_cast<float4*>(op + r * W_ + 4 * q) =
                *reinterpret_cast<const float4*>(&sOut[r * SOUT_LD + 4 * q]);
        }
    }
}

extern "C" void kernel_launch(void* const* d_in, const int* in_sizes, int n_in,
                              void* d_out, int out_size, void* d_ws, size_t ws_size,
                              hipStream_t stream) {
    // setup_inputs order: x, weight, bias, sign, padding, stride, func_type, alpha
    const float* x      = (const float*)d_in[0];
    const float* weight = (const float*)d_in[1];
    const float* bias   = (const float*)d_in[2];
    const float* sign   = (const float*)d_in[3];
    const int*   alpha  = (const int*)d_in[7];
    float* out = (float*)d_out;

    dim3 grid(NTILES, B_ * C_);
    morpho_fused<<<grid, TPB, 0, stream>>>(x, weight, bias, sign, alpha, out);
}

// Round 12
// 29.820 us; speedup vs baseline: 1.0621x; 1.0621x over previous
//
#include <hip/hip_runtime.h>
#include <math.h>

// Problem constants (fixed by setup_inputs)
constexpr int B_  = 8;
constexpr int C_  = 64;
constexpr int H_  = 112;
constexpr int W_  = 112;
constexpr int KH  = 5;
constexpr int KW  = 5;
constexpr int PAD = 2;

constexpr int TRT = 16;             // output rows per tile
constexpr int NT  = H_ / TRT;       // 7 tiles per plane
constexpr int LRT = TRT + KH - 1;   // 20 staged rows
constexpr int LCP = 118;            // float2 row stride (even -> rows 16B-aligned)
constexpr int TPB = 256;
constexpr int SOUT_LD = 116;        // f32 restage stride (mult of 4)
constexpr int NINT = LRT * 28;      // 560 interior float4 staging items
constexpr int NSTORE = TRT * 28;    // 448 output float4 items

// ---------------------------------------------------------------------------
// Persistent per-plane soft-morphology (func_type==1), factored softmax:
//   E = e^{a*s*x}, F = (s*x)*E  staged in double-buffered LDS (float2)
//   u_k = e^{a*w_k}, v_k = w_k*u_k  in registers, computed ONCE per block
//   out = s*( (corr(F,u)+corr(E,v)) * rcp(corr(E,u)) ) + s*bias
// One block per plane loops over 7 tiles; tile t+1's global loads are issued
// before tile t's compute so HBM/L2 latency hides under the FMA phase, and
// the prologue (sign/alpha/weight-exp) amortizes across the whole plane.
// ---------------------------------------------------------------------------
__global__ __launch_bounds__(TPB)
void morpho_persist(const float* __restrict__ x,
                    const float* __restrict__ weight,
                    const float* __restrict__ bias,
                    const float* __restrict__ sign,
                    const int*   __restrict__ alpha_p,
                    float* __restrict__ out)
{
    __shared__ __align__(16) float2 sEF[2][LRT][LCP];   // 2 x 18880 B
    __shared__ __align__(16) float  sOut[TRT * SOUT_LD]; // 7424 B

    const int plane = blockIdx.x;         // 0..511 (b*C + c)
    const int c     = plane & (C_ - 1);
    const int tid   = threadIdx.x;

    const float sg   = sign[0];
    const float seff = (fabsf(sg) >= 1e-7f) ? sg : 1.0f;
    const float a    = (float)alpha_p[0];
    const float aK   = a * seff;          // E = exp(aK * raw_x)

    const float* xp = x + (size_t)plane * (H_ * W_);
    float*       op = out + (size_t)plane * (H_ * W_);

    // per-item staging indices (fixed across iterations)
    int r_[3], q_[3];
    bool ok_[3];
#pragma unroll
    for (int k = 0; k < 3; ++k) {
        int i  = tid + TPB * k;               // 0..767
        int ic = (i < NINT) ? i : (NINT - 1);
        r_[k] = ic / 28;
        q_[k] = ic - 28 * r_[k];
        ok_[k] = (i < NINT);
    }

    // ---- prologue: issue tile-0 loads, then weight transforms (overlap) ----
    float4 xcur[3], xnxt[3];
#pragma unroll
    for (int k = 0; k < 3; ++k) {
        int grc = min(max(-PAD + r_[k], 0), H_ - 1);
        xcur[k] = *reinterpret_cast<const float4*>(xp + grc * W_ + 4 * q_[k]);
    }

    const float* wp = weight + c * (KH * KW);
    float su[KH * KW], sv[KH * KW];
#pragma unroll
    for (int k = 0; k < KH * KW; ++k) {
        float wv = wp[k];
        float u  = __expf(a * wv);
        su[k] = u;
        sv[k] = wv * u;
    }
    const float sb = seff * bias[c];

    const int ty = tid >> 4;      // 0..15 : output row within tile
    const int tx = tid & 15;      // 0..15 : col group
    const int c0 = tx * 7;

    for (int t = 0; t < NT; ++t) {
        const int row0 = t * TRT - PAD;
        float2 (*buf)[LCP] = sEF[t & 1];

        // ---- transform current tile's registers -> LDS ----
#pragma unroll
        for (int k = 0; k < 3; ++k) {
            if (ok_[k]) {
                int gr = row0 + r_[k];
                bool ok = (gr >= 0) && (gr < H_);
                float4 v = xcur[k];
                float e0 = ok ? __expf(aK * v.x) : 1.0f;
                float e1 = ok ? __expf(aK * v.y) : 1.0f;
                float e2 = ok ? __expf(aK * v.z) : 1.0f;
                float e3 = ok ? __expf(aK * v.w) : 1.0f;
                float f0 = ok ? (seff * v.x) * e0 : 0.0f;
                float f1 = ok ? (seff * v.y) * e1 : 0.0f;
                float f2 = ok ? (seff * v.z) * e2 : 0.0f;
                float f3 = ok ? (seff * v.w) * e3 : 0.0f;
                float4* dst = reinterpret_cast<float4*>(&buf[r_[k]][2 + 4 * q_[k]]);
                dst[0] = make_float4(e0, f0, e1, f1);
                dst[1] = make_float4(e2, f2, e3, f3);
            }
        }
        // halo columns (E=1, F=0): 20 rows x 2 sides
        if (tid < 2 * LRT) {
            int r  = tid >> 1;
            int fi = (tid & 1) ? 114 : 0;   // float2 col, 16B-aligned (LCP even)
            *reinterpret_cast<float4*>(&buf[r][fi]) = make_float4(1.0f, 0.0f, 1.0f, 0.0f);
        }

        // ---- issue next tile's global loads (land during compute) ----
        if (t + 1 < NT) {
            const int nrow0 = (t + 1) * TRT - PAD;
#pragma unroll
            for (int k = 0; k < 3; ++k) {
                int grc = min(max(nrow0 + r_[k], 0), H_ - 1);
                xnxt[k] = *reinterpret_cast<const float4*>(xp + grc * W_ + 4 * q_[k]);
            }
        }
        __syncthreads();

        // ---- compute: 1x7 outputs per thread, pure FMA + ds_read ----
        float Z[7], Nm[7];
#pragma unroll
        for (int o = 0; o < 7; ++o) { Z[o] = 0.0f; Nm[o] = 0.0f; }

#pragma unroll
        for (int rr = 0; rr < KH; ++rr) {
            float2 ew[11];
#pragma unroll
            for (int jj = 0; jj < 11; ++jj) ew[jj] = buf[ty + rr][c0 + jj];
#pragma unroll
            for (int j = 0; j < KW; ++j) {
                const float u = su[rr * 5 + j];
                const float v = sv[rr * 5 + j];
#pragma unroll
                for (int o = 0; o < 7; ++o) {
                    const float E = ew[o + j].x;
                    const float F = ew[o + j].y;
                    Z[o]  = fmaf(u, E, Z[o]);
                    Nm[o] = fmaf(u, F, fmaf(v, E, Nm[o]));
                }
            }
        }
#pragma unroll
        for (int o = 0; o < 7; ++o) {
            sOut[ty * SOUT_LD + c0 + o] =
                fmaf(seff * Nm[o], __builtin_amdgcn_rcpf(Z[o]), sb);
        }
        __syncthreads();

        // ---- coalesced float4 stores ----
        float* tb = op + (size_t)(t * TRT) * W_;
#pragma unroll
        for (int k = 0; k < 2; ++k) {
            int i = tid + TPB * k;
            if (i < NSTORE) {
                int r = i / 28;
                int q = i - 28 * r;
                *reinterpret_cast<float4*>(tb + r * W_ + 4 * q) =
                    *reinterpret_cast<const float4*>(&sOut[r * SOUT_LD + 4 * q]);
            }
        }

        // ---- rotate prefetched registers ----
#pragma unroll
        for (int k = 0; k < 3; ++k) xcur[k] = xnxt[k];
    }
}

extern "C" void kernel_launch(void* const* d_in, const int* in_sizes, int n_in,
                              void* d_out, int out_size, void* d_ws, size_t ws_size,
                              hipStream_t stream) {
    // setup_inputs order: x, weight, bias, sign, padding, stride, func_type, alpha
    const float* x      = (const float*)d_in[0];
    const float* weight = (const float*)d_in[1];
    const float* bias   = (const float*)d_in[2];
    const float* sign   = (const float*)d_in[3];
    const int*   alpha  = (const int*)d_in[7];
    float* out = (float*)d_out;

    dim3 grid(B_ * C_);   // one block per plane
    morpho_persist<<<grid, TPB, 0, stream>>>(x, weight, bias, sign, alpha, out);
}

// Round 15
// 24.718 us; speedup vs baseline: 1.2813x; 1.2064x over previous
//
#include <hip/hip_runtime.h>
#include <math.h>

typedef float v2f __attribute__((ext_vector_type(2)));

// Problem constants (fixed by setup_inputs)
constexpr int B_  = 8;
constexpr int C_  = 64;
constexpr int H_  = 112;
constexpr int W_  = 112;
constexpr int KH  = 5;
constexpr int KW  = 5;
constexpr int PAD = 2;

constexpr int TRT = 16;             // output rows per tile
constexpr int NT  = H_ / TRT;       // 7 tiles per plane
constexpr int LRT = TRT + KH - 1;   // 20 staged rows
constexpr int LCP = 118;            // v2f row stride (even -> rows 16B-aligned)
constexpr int TPB = 256;
constexpr int SOUT_LD = 116;        // f32 restage stride (mult of 4)
constexpr int NINT = LRT * 28;      // 560 interior float4 staging items
constexpr int NSTORE = TRT * 28;    // 448 output float4 items

// Execution barrier WITHOUT vmcnt drain: drain only LDS (lgkm), then raw
// s_barrier. Global loads/stores stay in flight across it (unlike
// __syncthreads, which emits s_waitcnt vmcnt(0) and serializes prefetch).
__device__ __forceinline__ void block_sync_lds() {
    asm volatile("s_waitcnt lgkmcnt(0)" ::: "memory");
    __builtin_amdgcn_sched_barrier(0);
    __builtin_amdgcn_s_barrier();
}

// ---------------------------------------------------------------------------
// Persistent per-plane soft-morphology (func_type==1), factored softmax:
//   E = e^{a*s*x}, F = (s*x)*E  staged in double-buffered LDS as (E,F) v2f
//   u_k = e^{a*w_k}, v_k = w_k*u_k  in registers (once per block)
//   (Z,Nm) += (u,u)*(E,F)  [v_pk_fma_f32] ;  nm2 += v*E  [scalar chain]
//   out = s*( (Nm+nm2) * rcp(Z) ) + s*bias
// Zero-padded taps => E=1, F=0.
// ---------------------------------------------------------------------------
__global__ __launch_bounds__(TPB)
void morpho_persist(const float* __restrict__ x,
                    const float* __restrict__ weight,
                    const float* __restrict__ bias,
                    const float* __restrict__ sign,
                    const int*   __restrict__ alpha_p,
                    float* __restrict__ out)
{
    __shared__ __align__(16) char  sraw[2 * LRT * LCP * sizeof(v2f)]; // 37760 B
    __shared__ __align__(16) float sOut[TRT * SOUT_LD];               // 7424 B
    v2f (*sEF)[LRT][LCP] = reinterpret_cast<v2f (*)[LRT][LCP]>(sraw);

    const int plane = blockIdx.x;         // 0..511 (b*C + c)
    const int c     = plane & (C_ - 1);
    const int tid   = threadIdx.x;

    const float sg   = sign[0];
    const float seff = (fabsf(sg) >= 1e-7f) ? sg : 1.0f;
    const float a    = (float)alpha_p[0];
    const float aK   = a * seff;          // E = exp(aK * raw_x)

    const float* xp = x + (size_t)plane * (H_ * W_);
    float*       op = out + (size_t)plane * (H_ * W_);

    // per-item staging indices (fixed across iterations)
    int r_[3], q_[3];
    bool ok_[3];
#pragma unroll
    for (int k = 0; k < 3; ++k) {
        int i  = tid + TPB * k;               // 0..767
        int ic = (i < NINT) ? i : (NINT - 1);
        r_[k] = ic / 28;
        q_[k] = ic - 28 * r_[k];
        ok_[k] = (i < NINT);
    }

    // ---- prologue: issue tile-0 loads, then weight transforms (overlap) ----
    float4 xcur[3], xnxt[3];
#pragma unroll
    for (int k = 0; k < 3; ++k) {
        int grc = min(max(-PAD + r_[k], 0), H_ - 1);
        xcur[k] = *reinterpret_cast<const float4*>(xp + grc * W_ + 4 * q_[k]);
    }

    const float* wp = weight + c * (KH * KW);
    float su[KH * KW], sv[KH * KW];
#pragma unroll
    for (int k = 0; k < KH * KW; ++k) {
        float wv = wp[k];
        float u  = __expf(a * wv);
        su[k] = u;
        sv[k] = wv * u;
    }
    const float sb = seff * bias[c];

    const int ty = tid >> 4;      // 0..15 : output row within tile
    const int tx = tid & 15;      // 0..15 : col group
    const int c0 = tx * 7;

    for (int t = 0; t < NT; ++t) {
        const int row0 = t * TRT - PAD;
        v2f (*buf)[LCP] = sEF[t & 1];

        // ---- transform current tile's registers -> LDS ----
#pragma unroll
        for (int k = 0; k < 3; ++k) {
            if (ok_[k]) {
                int gr = row0 + r_[k];
                bool ok = (gr >= 0) && (gr < H_);
                float4 v = xcur[k];
                float e0 = ok ? __expf(aK * v.x) : 1.0f;
                float e1 = ok ? __expf(aK * v.y) : 1.0f;
                float e2 = ok ? __expf(aK * v.z) : 1.0f;
                float e3 = ok ? __expf(aK * v.w) : 1.0f;
                float f0 = ok ? (seff * v.x) * e0 : 0.0f;
                float f1 = ok ? (seff * v.y) * e1 : 0.0f;
                float f2 = ok ? (seff * v.z) * e2 : 0.0f;
                float f3 = ok ? (seff * v.w) * e3 : 0.0f;
                float4* dst = reinterpret_cast<float4*>(&buf[r_[k]][2 + 4 * q_[k]]);
                dst[0] = make_float4(e0, f0, e1, f1);
                dst[1] = make_float4(e2, f2, e3, f3);
            }
        }
        // halo columns (E=1, F=0): 20 rows x 2 sides
        if (tid < 2 * LRT) {
            int r  = tid >> 1;
            int fi = (tid & 1) ? 114 : 0;   // v2f col, 16B-aligned (LCP even)
            *reinterpret_cast<float4*>(&buf[r][fi]) = make_float4(1.0f, 0.0f, 1.0f, 0.0f);
        }

        // ---- issue next tile's global loads (stay in flight across barrier) ----
        if (t + 1 < NT) {
            const int nrow0 = (t + 1) * TRT - PAD;
#pragma unroll
            for (int k = 0; k < 3; ++k) {
                int grc = min(max(nrow0 + r_[k], 0), H_ - 1);
                xnxt[k] = *reinterpret_cast<const float4*>(xp + grc * W_ + 4 * q_[k]);
            }
        }
        block_sync_lds();   // lgkm drain + raw s_barrier; NO vmcnt drain

        // ---- compute: 7 outputs/thread; packed (Z,Nm) FMA + scalar vE chain ----
        v2f   acc[7];
        float nm2[7];
#pragma unroll
        for (int o = 0; o < 7; ++o) { acc[o] = (v2f){0.0f, 0.0f}; nm2[o] = 0.0f; }

#pragma unroll
        for (int rr = 0; rr < KH; ++rr) {
            v2f ew[11];
#pragma unroll
            for (int jj = 0; jj < 11; ++jj) ew[jj] = buf[ty + rr][c0 + jj];
#pragma unroll
            for (int j = 0; j < KW; ++j) {
                const float u  = su[rr * 5 + j];
                const v2f   u2 = (v2f){u, u};
                const float v  = sv[rr * 5 + j];
#pragma unroll
                for (int o = 0; o < 7; ++o) {
                    acc[o] = __builtin_elementwise_fma(u2, ew[o + j], acc[o]); // Z+=uE, Nm+=uF
                    nm2[o] = fmaf(v, ew[o + j].x, nm2[o]);                     // nm2+=vE
                }
            }
        }
#pragma unroll
        for (int o = 0; o < 7; ++o) {
            float Z  = acc[o].x;
            float Nm = acc[o].y + nm2[o];
            sOut[ty * SOUT_LD + c0 + o] = fmaf(seff * Nm, __builtin_amdgcn_rcpf(Z), sb);
        }
        block_sync_lds();

        // ---- coalesced float4 stores (fire-and-forget) ----
        float* tb = op + (size_t)(t * TRT) * W_;
#pragma unroll
        for (int k = 0; k < 2; ++k) {
            int i = tid + TPB * k;
            if (i < NSTORE) {
                int r = i / 28;
                int q = i - 28 * r;
                *reinterpret_cast<float4*>(tb + r * W_ + 4 * q) =
                    *reinterpret_cast<const float4*>(&sOut[r * SOUT_LD + 4 * q]);
            }
        }

        // ---- rotate prefetched registers (vmcnt wait lands HERE, post-compute) ----
#pragma unroll
        for (int k = 0; k < 3; ++k) xcur[k] = xnxt[k];
    }
}

extern "C" void kernel_launch(void* const* d_in, const int* in_sizes, int n_in,
                              void* d_out, int out_size, void* d_ws, size_t ws_size,
                              hipStream_t stream) {
    // setup_inputs order: x, weight, bias, sign, padding, stride, func_type, alpha
    const float* x      = (const float*)d_in[0];
    const float* weight = (const float*)d_in[1];
    const float* bias   = (const float*)d_in[2];
    const float* sign   = (const float*)d_in[3];
    const int*   alpha  = (const int*)d_in[7];
    float* out = (float*)d_out;

    dim3 grid(B_ * C_);   // one block per plane
    morpho_persist<<<grid, TPB, 0, stream>>>(x, weight, bias, sign, alpha, out);
}